// Round 5
// baseline (1584.529 us; speedup 1.0000x reference)
//
#include <hip/hip_runtime.h>
#include <stdint.h>

// LSTM (packed sequence) on MI355X — round 5.
// T=512, B=64, D=512, H=512. out[t,b,:] = masked h_t.
// 256 WGs = 8 groups (8 batch rows) x 32 jblk (16 hidden cols).
// Cross-WG h exchange: SELF-DESCRIBING TAGGED DATA (bit14/bit30 of each
// packed (hi,lo) bf16 dword carry a 2-bit step tag; |h|<=1 makes bit14
// of both halves provably 0). DUAL-COPY transport:
//   (1) local buffer, plain stores -> producer XCD's L2. Consumers poll
//       with BOUNDED atomic fetch_add(0) (RMW => at least L2, never L1-
//       stale). If group is XCD-pure (blockIdx%8 round-robin), detect
//       latency ~L2 RTT instead of LLC RTT.
//   (2) LLC buffer, agent-scope stores — the PROVEN R4 path, polled
//       unboundedly on local timeout => liveness never depends on any
//       unverified cache semantics. Sticky use_local=false after one
//       timeout kills cross-XCD stale-tag aliasing (disable happens at
//       t=1 while the local line still holds non-matching init tag 3).
//   - bf16 3-split MFMA (hi/lo), fp32-class accuracy (proven R1-R4).
//   - Weight fragments persistent in VGPRs/AGPRs (build_frags).
//   - x-projection GEMM for t+1 in step t's tail (off the serial path).

#define TT 512
#define BB 64
#define DD 512
#define HH 512
#define NWG 256
#define NTHR 512
#define GR 8   // batch rows per group

typedef short short8 __attribute__((ext_vector_type(8)));
typedef float f32x4 __attribute__((ext_vector_type(4)));

__device__ __forceinline__ uint16_t bf16_rne(float f) {
  uint32_t u = __float_as_uint(f);
  u += 0x7fffu + ((u >> 16) & 1u);
  return (uint16_t)(u >> 16);
}

__device__ __forceinline__ void split2(float f, uint16_t &hi, uint16_t &lo) {
  uint16_t h = bf16_rne(f);
  hi = h;
  lo = bf16_rne(f - __uint_as_float(((uint32_t)h) << 16));
}

__device__ __forceinline__ float sigf(float v) { return 1.0f / (1.0f + __expf(-v)); }
__device__ __forceinline__ float tanh_(float v) {
  return 1.0f - 2.0f / (__expf(2.0f * v) + 1.0f);
}

// Build MFMA B-fragment buffer from W [2048][512] (row-major, k contiguous).
// B-frag lane layout for mfma_f32_16x16x32_bf16: col = lane&15,
// k = ks*32 + (lane>>4)*8 + j (8 contiguous k per lane).
__global__ void build_frags(const float* __restrict__ W, uint32_t* __restrict__ frag) {
  const int tid = blockIdx.x * 256 + threadIdx.x;   // 0..131071
  const int lane = tid & 63;
  const int ks = (tid >> 6) & 15;
  const int nblk = tid >> 10;                        // 0..127
  const int col = nblk * 16 + (lane & 15);
  const int k0 = ks * 32 + ((lane >> 4) << 3);
  const float* src = W + (size_t)col * 512 + k0;
  float4 a = *(const float4*)(src);
  float4 b = *(const float4*)(src + 4);
  float v[8] = {a.x, a.y, a.z, a.w, b.x, b.y, b.z, b.w};
  uint32_t hw[4], lw[4];
#pragma unroll
  for (int j = 0; j < 4; ++j) {
    uint16_t h0, l0, h1, l1;
    split2(v[2 * j], h0, l0);
    split2(v[2 * j + 1], h1, l1);
    hw[j] = (uint32_t)h0 | ((uint32_t)h1 << 16);
    lw[j] = (uint32_t)l0 | ((uint32_t)l1 << 16);
  }
  uint4* dst = (uint4*)(frag + (size_t)tid * 8);
  dst[0] = make_uint4(hw[0], hw[1], hw[2], hw[3]);
  dst[1] = make_uint4(lw[0], lw[1], lw[2], lw[3]);
}

__global__ __launch_bounds__(NTHR, 2) void lstm_main(
    const float* __restrict__ x, const int* __restrict__ len,
    const float* __restrict__ bias, const uint32_t* __restrict__ fragWx,
    const uint32_t* __restrict__ fragWh, uint32_t* __restrict__ h_pair,
    uint32_t* __restrict__ h_loc, float* __restrict__ out) {
  const int tid = threadIdx.x;
  const int lane = tid & 63;
  const int wave = tid >> 6;      // 0..7
  const int gp = wave >> 1;       // gate 0..3 (i,f,c,o)
  const int kh = wave & 1;        // K half
  const int group = blockIdx.x & 7;
  const int jblk = blockIdx.x >> 3;   // 0..31
  const int b0 = group * GR;
  const int j0 = jblk << 4;
  uint32_t* hbase = h_pair + (size_t)group * 2 * (GR * HH);
  uint32_t* lbase = h_loc + (size_t)group * 2 * (GR * HH);

  __shared__ uint16_t AH[GR * 512];   // 8 KB
  __shared__ uint16_t AL[GR * 512];   // 8 KB
  __shared__ float ex[8][GR][16];     // 4 KB
  __shared__ float c_st[GR][16];
  __shared__ float h_st[GR][16];
  __shared__ float bias_l[4][16];
  __shared__ int len_l[GR];

  if (tid < GR * 16) {
    c_st[tid >> 4][tid & 15] = 0.0f;
    h_st[tid >> 4][tid & 15] = 0.0f;
  }
  if (tid < 64) bias_l[tid >> 4][tid & 15] = bias[(size_t)(tid >> 4) * HH + j0 + (tid & 15)];
  if (tid < GR) len_l[tid] = len[b0 + tid];

  // Persistent B fragments: this wave's gate, this jblk, its K half.
  short8 bxh[8], bxl[8], bhh[8], bhl[8];
  {
    const int nblk = gp * 32 + jblk;
#pragma unroll
    for (int ksl = 0; ksl < 8; ++ksl) {
      const size_t idx = ((size_t)(nblk * 16 + kh * 8 + ksl) * 64 + lane) * 8;
      uint4 vh = *(const uint4*)(fragWx + idx);
      uint4 vl = *(const uint4*)(fragWx + idx + 4);
      bxh[ksl] = __builtin_bit_cast(short8, vh);
      bxl[ksl] = __builtin_bit_cast(short8, vl);
      uint4 wh = *(const uint4*)(fragWh + idx);
      uint4 wl = *(const uint4*)(fragWh + idx + 4);
      bhh[ksl] = __builtin_bit_cast(short8, wh);
      bhl[ksl] = __builtin_bit_cast(short8, wl);
    }
  }

  // A-frag addressing: row = (lane&7) (MFMA M rows 8-15 duplicate 0-7; their
  // C rows are discarded). 16B chunk = (lane>>4)*16, XOR swizzle row<<4.
  const int arow = lane & 7;
  const int achk = (lane >> 4) << 4;
  const int axr = arow << 4;
  const char* rowH = (const char*)AH + arow * 1024;
  const char* rowL = (const char*)AL + arow * 1024;

  f32x4 hh = {0.f, 0.f, 0.f, 0.f}, lh = {0.f, 0.f, 0.f, 0.f}, hl = {0.f, 0.f, 0.f, 0.f};
  float4 xp[2];
  bool use_local = true;   // sticky: first local timeout disables local polls

#define LOAD_XP(tt)                                                            \
  _Pragma("unroll") for (int i = 0; i < 2; ++i) {                              \
    const int flat4 = i * 2048 + tid * 4;                                      \
    const int row = flat4 >> 9;                                                \
    const int col = flat4 & 511;                                               \
    xp[i] = *(const float4*)(x + ((size_t)(tt) * BB + b0 + row) * DD + col);   \
  }

#define STAGE_XP()                                                             \
  _Pragma("unroll") for (int i = 0; i < 2; ++i) {                              \
    const int flat4 = i * 2048 + tid * 4;                                      \
    const int row = flat4 >> 9;                                                \
    const int col = flat4 & 511;                                               \
    uint16_t h0, l0, h1, l1, h2, l2, h3, l3;                                   \
    split2(xp[i].x, h0, l0);                                                   \
    split2(xp[i].y, h1, l1);                                                   \
    split2(xp[i].z, h2, l2);                                                   \
    split2(xp[i].w, h3, l3);                                                   \
    const uint32_t hw0 = (uint32_t)h0 | ((uint32_t)h1 << 16);                  \
    const uint32_t hw1 = (uint32_t)h2 | ((uint32_t)h3 << 16);                  \
    const uint32_t lw0 = (uint32_t)l0 | ((uint32_t)l1 << 16);                  \
    const uint32_t lw1 = (uint32_t)l2 | ((uint32_t)l3 << 16);                  \
    const int off = row * 1024 + ((col * 2) ^ (row << 4));                     \
    *(uint2*)((char*)AH + off) = make_uint2(hw0, hw1);                         \
    *(uint2*)((char*)AL + off) = make_uint2(lw0, lw1);                         \
  }

#define X_MFMA()                                                               \
  hh = (f32x4){0.f, 0.f, 0.f, 0.f};                                           \
  lh = (f32x4){0.f, 0.f, 0.f, 0.f};                                           \
  hl = (f32x4){0.f, 0.f, 0.f, 0.f};                                           \
  _Pragma("unroll") for (int ksl = 0; ksl < 8; ++ksl) {                        \
    const int off = ((kh * 8 + ksl) * 64 + achk) ^ axr;                        \
    short8 ah = *(const short8*)(rowH + off);                                  \
    short8 al = *(const short8*)(rowL + off);                                  \
    hh = __builtin_amdgcn_mfma_f32_16x16x32_bf16(ah, bxh[ksl], hh, 0, 0, 0);   \
    lh = __builtin_amdgcn_mfma_f32_16x16x32_bf16(al, bxh[ksl], lh, 0, 0, 0);   \
    hl = __builtin_amdgcn_mfma_f32_16x16x32_bf16(ah, bxl[ksl], hl, 0, 0, 0);   \
  }

  // ---- prologue: xacc for t=0, prefetch x_1 ----
  LOAD_XP(0);
  __syncthreads();
  STAGE_XP();
  __syncthreads();
  X_MFMA();
  LOAD_XP(1);

  for (int t = 0; t < TT; ++t) {
    const int rbuf = t & 1;
    const int wbuf = rbuf ^ 1;

    if (t > 0) {
      // --- acquire tagged h_{t-1} (this thread's 8 dwords) ---
      const uint32_t tagp = (((uint32_t)(t - 1)) >> 1) & 3u;
      const uint32_t EXd = ((tagp & 1u) << 14) | ((tagp >> 1) << 30);
      const uint64_t EX2 = ((uint64_t)EXd << 32) | EXd;
      const uint64_t MK2 = 0x4000400040004000ull;
      uint64_t w0, w1, w2, w3;
      bool got = false;

      if (use_local) {
        // bounded L2 poll: atomic RMW cannot be satisfied from L1.
        unsigned long long* lp =
            (unsigned long long*)(lbase + (size_t)rbuf * (GR * HH)) +
            (size_t)tid * 4;
        int tries = (t == 1) ? 256 : 16;
        do {
          w0 = __hip_atomic_fetch_add(lp + 0, 0ull, __ATOMIC_RELAXED,
                                      __HIP_MEMORY_SCOPE_WORKGROUP);
          w1 = __hip_atomic_fetch_add(lp + 1, 0ull, __ATOMIC_RELAXED,
                                      __HIP_MEMORY_SCOPE_WORKGROUP);
          w2 = __hip_atomic_fetch_add(lp + 2, 0ull, __ATOMIC_RELAXED,
                                      __HIP_MEMORY_SCOPE_WORKGROUP);
          w3 = __hip_atomic_fetch_add(lp + 3, 0ull, __ATOMIC_RELAXED,
                                      __HIP_MEMORY_SCOPE_WORKGROUP);
          got = ((((w0 ^ EX2) | (w1 ^ EX2) | (w2 ^ EX2) | (w3 ^ EX2)) & MK2) ==
                 0ull);
        } while (!got && --tries);
        if (!got) use_local = false;   // sticky — prevents stale-tag aliasing
      }

      if (!got) {
        // unbounded LLC poll — the proven R4 liveness path.
        const unsigned long long* pb =
            (const unsigned long long*)(hbase + (size_t)rbuf * (GR * HH)) +
            (size_t)tid * 4;
        for (;;) {
          w0 = __hip_atomic_load(pb + 0, __ATOMIC_RELAXED, __HIP_MEMORY_SCOPE_AGENT);
          w1 = __hip_atomic_load(pb + 1, __ATOMIC_RELAXED, __HIP_MEMORY_SCOPE_AGENT);
          w2 = __hip_atomic_load(pb + 2, __ATOMIC_RELAXED, __HIP_MEMORY_SCOPE_AGENT);
          w3 = __hip_atomic_load(pb + 3, __ATOMIC_RELAXED, __HIP_MEMORY_SCOPE_AGENT);
          const uint64_t bad =
              (((w0 ^ EX2) | (w1 ^ EX2) | (w2 ^ EX2) | (w3 ^ EX2)) & MK2);
          if (bad == 0ull) break;
        }
      }
      __syncthreads();   // all waves have their data; prev tail X_MFMA done

      // --- clear tags, pack, store to LDS tile (swizzled) ---
      {
        const uint32_t CM = ~0x40004000u;
        uint32_t d0 = (uint32_t)w0 & CM, d1 = (uint32_t)(w0 >> 32) & CM;
        uint32_t d2 = (uint32_t)w1 & CM, d3 = (uint32_t)(w1 >> 32) & CM;
        uint32_t d4 = (uint32_t)w2 & CM, d5 = (uint32_t)(w2 >> 32) & CM;
        uint32_t d6 = (uint32_t)w3 & CM, d7 = (uint32_t)(w3 >> 32) & CM;
        const uint32_t hi0 = (d0 & 0xFFFFu) | (d1 << 16);
        const uint32_t lo0 = (d0 >> 16) | (d1 & 0xFFFF0000u);
        const uint32_t hi1 = (d2 & 0xFFFFu) | (d3 << 16);
        const uint32_t lo1 = (d2 >> 16) | (d3 & 0xFFFF0000u);
        const uint32_t hi2 = (d4 & 0xFFFFu) | (d5 << 16);
        const uint32_t lo2 = (d4 >> 16) | (d5 & 0xFFFF0000u);
        const uint32_t hi3 = (d6 & 0xFFFFu) | (d7 << 16);
        const uint32_t lo3 = (d6 >> 16) | (d7 & 0xFFFF0000u);
        const int woff = wave * 1024 + ((lane * 16) ^ (wave << 4));
        *(uint4*)((char*)AH + woff) = make_uint4(hi0, hi1, hi2, hi3);
        *(uint4*)((char*)AL + woff) = make_uint4(lo0, lo1, lo2, lo3);
      }
      __syncthreads();

      // --- h MFMA ---
#pragma unroll
      for (int ksl = 0; ksl < 8; ++ksl) {
        const int off = ((kh * 8 + ksl) * 64 + achk) ^ axr;
        short8 ah = *(const short8*)(rowH + off);
        short8 al = *(const short8*)(rowL + off);
        hh = __builtin_amdgcn_mfma_f32_16x16x32_bf16(ah, bhh[ksl], hh, 0, 0, 0);
        lh = __builtin_amdgcn_mfma_f32_16x16x32_bf16(al, bhh[ksl], lh, 0, 0, 0);
        hl = __builtin_amdgcn_mfma_f32_16x16x32_bf16(ah, bhl[ksl], hl, 0, 0, 0);
      }
    }

    // --- exchange partial preacts (C rows 0-7 only) ---
    {
      const int crow = (lane >> 4) << 2;
      const int ccol = lane & 15;
      if (crow < GR) {
#pragma unroll
        for (int r = 0; r < 4; ++r) ex[wave][crow + r][ccol] = hh[r] + lh[r] + hl[r];
      }
    }
    __syncthreads();   // S1: ex ready; tile free

    // --- cell update (8x16 = 128 threads); dual tagged h store ---
    if (tid < GR * 16) {
      const int brow = tid >> 4;
      const int jc = tid & 15;
      const float p0 = ex[0][brow][jc] + ex[1][brow][jc] + bias_l[0][jc];
      const float p1 = ex[2][brow][jc] + ex[3][brow][jc] + bias_l[1][jc];
      const float p2 = ex[4][brow][jc] + ex[5][brow][jc] + bias_l[2][jc];
      const float p3 = ex[6][brow][jc] + ex[7][brow][jc] + bias_l[3][jc];
      const float ig = sigf(p0);
      const float fg = sigf(p1);
      const float cc = tanh_(p2);
      const float og = sigf(p3);
      const float co = c_st[brow][jc];
      const float ct = fg * co + ig * cc;
      const float ht = og * tanh_(ct);
      const bool m = (t < len_l[brow]);
      const float cn = m ? ct : co;
      const float hn = m ? ht : h_st[brow][jc];
      c_st[brow][jc] = cn;
      h_st[brow][jc] = hn;
      out[((size_t)t * BB + b0 + brow) * HH + j0 + jc] = m ? ht : 0.0f;
      uint16_t ph, pl;
      split2(hn, ph, pl);   // |hn| <= 1.0 -> bit14 of ph and pl are 0
      const uint32_t tagw = (((uint32_t)t) >> 1) & 3u;
      const uint32_t TB = ((tagw & 1u) << 14) | ((tagw >> 1) << 30);
      const uint32_t hv = ((uint32_t)ph | ((uint32_t)pl << 16)) | TB;
      const size_t eoff = (size_t)wbuf * (GR * HH) + brow * HH + j0 + jc;
      __hip_atomic_store(lbase + eoff, hv, __ATOMIC_RELAXED,
                         __HIP_MEMORY_SCOPE_WORKGROUP);   // -> local L2
      __hip_atomic_store(hbase + eoff, hv, __ATOMIC_RELAXED,
                         __HIP_MEMORY_SCOPE_AGENT);       // -> LLC (fallback)
    }

    if (t + 1 < TT) {
      STAGE_XP();        // stage x_{t+1}
      __syncthreads();   // S2
      X_MFMA();          // xacc for t+1 — off the serial h path
      LOAD_XP(min(t + 2, TT - 1));
    }
  }
}

extern "C" void kernel_launch(void* const* d_in, const int* in_sizes, int n_in,
                              void* d_out, int out_size, void* d_ws, size_t ws_size,
                              hipStream_t stream) {
  const float* x = (const float*)d_in[0];
  const int* len = (const int*)d_in[1];
  const float* Wx = (const float*)d_in[2];    // [2048][512]
  const float* Wh = (const float*)d_in[3];    // [2048][512]
  const float* bias = (const float*)d_in[4];  // [2048]
  float* out = (float*)d_out;

  const size_t FRAG_DW = (size_t)128 * 16 * 64 * 8;  // 1M dwords = 4 MB
  const size_t HP_DW = (size_t)8 * 2 * GR * HH;      // 64K dwords = 256 KB
  uint32_t* fragWx = (uint32_t*)d_ws;
  uint32_t* fragWh = fragWx + FRAG_DW;
  uint32_t* h_pair = fragWh + FRAG_DW;               // LLC exchange buffer
  uint32_t* h_loc = h_pair + HP_DW;                  // XCD-local exchange buffer

  // 0xFF pattern -> tag bits = 3 in every dword; never matches the first
  // expected tags (0,0,1,1,2,2) and overwritten >=2x before tag 3 recurs.
  hipMemsetAsync(h_pair, 0xFF, HP_DW * 4, stream);
  hipMemsetAsync(h_loc, 0xFF, HP_DW * 4, stream);

  build_frags<<<dim3(512), dim3(256), 0, stream>>>(Wx, fragWx);
  build_frags<<<dim3(512), dim3(256), 0, stream>>>(Wh, fragWh);

  void* args[] = {(void*)&x,      (void*)&len,   (void*)&bias, (void*)&fragWx,
                  (void*)&fragWh, (void*)&h_pair, (void*)&h_loc, (void*)&out};
  hipLaunchCooperativeKernel((void*)lstm_main, dim3(NWG), dim3(NTHR), args, 0, stream);
}

// Round 6
// 1438.891 us; speedup vs baseline: 1.1012x; 1.1012x over previous
//
#include <hip/hip_runtime.h>
#include <stdint.h>

// LSTM (packed sequence) on MI355X — round 6.
// T=512, B=64, D=512, H=512. out[t,b,:] = masked h_t.
//
// Structure:
//   1) build_frags(Wx), build_frags(Wh): fp32 -> hi/lo bf16 MFMA B-fragments.
//   2) xg_gemm: one-shot xg[t,b,g] = x@Wx^T + b (fp32, 256 MB in d_ws).
//      Removes the x-projection (half the MFMA issue) from the recurrence.
//   3) lstm2 (cooperative, 128 WGs = 4 groups x 32 jblk): recurrence only.
//      GR=16 batch rows/group -> MFMA M dim fully used (no 2x duplication).
//      Cross-WG h exchange: R4's proven SELF-DESCRIBING TAGGED DATA at LLC
//      (bit14/bit30 of each packed (hi,lo) bf16 dword carry a 2-bit step
//      tag; |h|<=1 makes those bits provably 0). Double-buffered by step
//      parity; consumers poll data dwords directly (no flags, no drains).
//   Fallback: if ws_size can't hold xg, launch the verbatim R4 kernel.
//
//   bf16 3-split MFMA (hi/lo) everywhere: fp32-class accuracy (absmax
//   ~4e-3 vs 1.9e-2 threshold, proven R1-R5).

#define TT 512
#define BB 64
#define DD 512
#define HH 512
#define NTHR 512
// new path
#define NWG2 128
#define GR2 16
// fallback path (R4)
#define NWG4 256
#define GR4 8

typedef short short8 __attribute__((ext_vector_type(8)));
typedef float f32x4 __attribute__((ext_vector_type(4)));

__device__ __forceinline__ uint16_t bf16_rne(float f) {
  uint32_t u = __float_as_uint(f);
  u += 0x7fffu + ((u >> 16) & 1u);
  return (uint16_t)(u >> 16);
}

__device__ __forceinline__ void split2(float f, uint16_t &hi, uint16_t &lo) {
  uint16_t h = bf16_rne(f);
  hi = h;
  lo = bf16_rne(f - __uint_as_float(((uint32_t)h) << 16));
}

__device__ __forceinline__ float sigf(float v) { return 1.0f / (1.0f + __expf(-v)); }
__device__ __forceinline__ float tanh_(float v) {
  return 1.0f - 2.0f / (__expf(2.0f * v) + 1.0f);
}

// Build MFMA B-fragment buffer from W [2048][512] (row-major, k contiguous).
// frag[nblk][ks][lane][0..3]=hi dwords, [4..7]=lo dwords. B-frag lane layout
// for mfma_f32_16x16x32_bf16: col = lane&15, k = ks*32 + (lane>>4)*8 + j.
__global__ void build_frags(const float* __restrict__ W, uint32_t* __restrict__ frag) {
  const int tid = blockIdx.x * 256 + threadIdx.x;   // 0..131071
  const int lane = tid & 63;
  const int ks = (tid >> 6) & 15;
  const int nblk = tid >> 10;                        // 0..127
  const int col = nblk * 16 + (lane & 15);
  const int k0 = ks * 32 + ((lane >> 4) << 3);
  const float* src = W + (size_t)col * 512 + k0;
  float4 a = *(const float4*)(src);
  float4 b = *(const float4*)(src + 4);
  float v[8] = {a.x, a.y, a.z, a.w, b.x, b.y, b.z, b.w};
  uint32_t hw[4], lw[4];
#pragma unroll
  for (int j = 0; j < 4; ++j) {
    uint16_t h0, l0, h1, l1;
    split2(v[2 * j], h0, l0);
    split2(v[2 * j + 1], h1, l1);
    hw[j] = (uint32_t)h0 | ((uint32_t)h1 << 16);
    lw[j] = (uint32_t)l0 | ((uint32_t)l1 << 16);
  }
  uint4* dst = (uint4*)(frag + (size_t)tid * 8);
  dst[0] = make_uint4(hw[0], hw[1], hw[2], hw[3]);
  dst[1] = make_uint4(lw[0], lw[1], lw[2], lw[3]);
}

// One-shot xg[t] = x[t] @ Wx^T + b, fp32 out. One WG per t, 8 waves =
// 4 gates x 2 jsub; each wave full K=512 (no partial sums).
__global__ __launch_bounds__(NTHR, 1) void xg_gemm(
    const float* __restrict__ x, const float* __restrict__ bias,
    const uint32_t* __restrict__ fragWx, float* __restrict__ xg) {
  const int t = blockIdx.x;
  const int tid = threadIdx.x;
  const int lane = tid & 63;
  const int wave = tid >> 6;
  const int gate = wave & 3;
  const int jsub = wave >> 2;

  __shared__ uint16_t AH[64 * 512];   // 64 KB
  __shared__ uint16_t AL[64 * 512];   // 64 KB

  // stage x[t] (64x512 fp32) -> hi/lo bf16 tiles, XOR-swizzled rows
#pragma unroll
  for (int i = 0; i < 16; ++i) {
    const int flat4 = i * 2048 + tid * 4;
    const int row = flat4 >> 9;
    const int col = flat4 & 511;
    float4 v = *(const float4*)(x + ((size_t)t * BB + row) * DD + col);
    uint16_t h0, l0, h1, l1, h2, l2, h3, l3;
    split2(v.x, h0, l0);
    split2(v.y, h1, l1);
    split2(v.z, h2, l2);
    split2(v.w, h3, l3);
    const int off = row * 1024 + ((col * 2) ^ ((row & 7) << 4));
    *(uint2*)((char*)AH + off) =
        make_uint2((uint32_t)h0 | ((uint32_t)h1 << 16), (uint32_t)h2 | ((uint32_t)h3 << 16));
    *(uint2*)((char*)AL + off) =
        make_uint2((uint32_t)l0 | ((uint32_t)l1 << 16), (uint32_t)l2 | ((uint32_t)l3 << 16));
  }
  __syncthreads();

  const int achk = (lane >> 4) << 4;
  const int axr = (lane & 7) << 4;   // (arow&7)<<4; arow = m*16 + (lane&15)

  for (int jp = 0; jp < 16; ++jp) {
    const int jblk = jp * 2 + jsub;
    const int nblk = gate * 32 + jblk;
    short8 bh[16], bl[16];
#pragma unroll
    for (int ks = 0; ks < 16; ++ks) {
      const size_t idx = ((size_t)(nblk * 16 + ks) * 64 + lane) * 8;
      bh[ks] = __builtin_bit_cast(short8, *(const uint4*)(fragWx + idx));
      bl[ks] = __builtin_bit_cast(short8, *(const uint4*)(fragWx + idx + 4));
    }
    const int colg = (nblk << 4) + (lane & 15);
    const float bv = bias[colg];
    for (int m = 0; m < 4; ++m) {
      const char* rowH = (const char*)AH + (m * 16 + (lane & 15)) * 1024;
      const char* rowL = (const char*)AL + (m * 16 + (lane & 15)) * 1024;
      f32x4 hh = {0.f, 0.f, 0.f, 0.f}, lh = {0.f, 0.f, 0.f, 0.f}, hl = {0.f, 0.f, 0.f, 0.f};
#pragma unroll
      for (int ks = 0; ks < 16; ++ks) {
        const int off = (ks * 64 + achk) ^ axr;
        short8 ah = *(const short8*)(rowH + off);
        short8 al = *(const short8*)(rowL + off);
        hh = __builtin_amdgcn_mfma_f32_16x16x32_bf16(ah, bh[ks], hh, 0, 0, 0);
        lh = __builtin_amdgcn_mfma_f32_16x16x32_bf16(al, bh[ks], lh, 0, 0, 0);
        hl = __builtin_amdgcn_mfma_f32_16x16x32_bf16(ah, bl[ks], hl, 0, 0, 0);
      }
      const int r0 = m * 16 + ((lane >> 4) << 2);   // C: row=(lane>>4)*4+i, col=lane&15
#pragma unroll
      for (int i = 0; i < 4; ++i)
        xg[((size_t)t * BB + r0 + i) * 2048 + colg] = hh[i] + lh[i] + hl[i] + bv;
    }
  }
}

// Recurrence-only cooperative kernel. 128 WGs = 4 groups(16 rows) x 32 jblk.
__global__ __launch_bounds__(NTHR, 2) void lstm2(
    const int* __restrict__ len, const uint32_t* __restrict__ fragWh,
    const float* __restrict__ xg, uint32_t* __restrict__ h_pair,
    float* __restrict__ out) {
  const int tid = threadIdx.x;
  const int lane = tid & 63;
  const int wave = tid >> 6;      // 0..7
  const int gp = wave >> 1;       // gate 0..3 (i,f,c,o)
  const int kh = wave & 1;        // K half
  const int group = blockIdx.x & 3;
  const int jblk = blockIdx.x >> 2;   // 0..31
  const int b0 = group * GR2;
  const int j0 = jblk << 4;
  uint32_t* hbase = h_pair + (size_t)group * 2 * (GR2 * HH);

  __shared__ uint16_t AH[GR2 * 512];   // 16 KB
  __shared__ uint16_t AL[GR2 * 512];   // 16 KB
  __shared__ float ex[8][GR2][16];     // 8 KB
  __shared__ float c_st[GR2][16];
  __shared__ float h_st[GR2][16];
  __shared__ int len_l[GR2];

  if (tid < GR2 * 16) {
    c_st[tid >> 4][tid & 15] = 0.0f;
    h_st[tid >> 4][tid & 15] = 0.0f;
  }
  if (tid < GR2) len_l[tid] = len[b0 + tid];

  // Persistent Wh fragments: this wave's gate, this jblk, its K half.
  short8 bhh[8], bhl[8];
  {
    const int nblk = gp * 32 + jblk;
#pragma unroll
    for (int ksl = 0; ksl < 8; ++ksl) {
      const size_t idx = ((size_t)(nblk * 16 + kh * 8 + ksl) * 64 + lane) * 8;
      bhh[ksl] = __builtin_bit_cast(short8, *(const uint4*)(fragWh + idx));
      bhl[ksl] = __builtin_bit_cast(short8, *(const uint4*)(fragWh + idx + 4));
    }
  }

  // A-frag addressing: row = lane&15 (all 16 real), chunk = (lane>>4)*16 B.
  const int arow = lane & 15;
  const int achk = (lane >> 4) << 4;
  const int axr = (arow & 7) << 4;
  const char* rowH = (const char*)AH + arow * 1024;
  const char* rowL = (const char*)AL + arow * 1024;

  // cell-thread coords (valid when tid<256)
  const int brow = tid >> 4;
  const int jc = tid & 15;

  // xg prefetch registers
  float xc0 = 0.f, xc1 = 0.f, xc2 = 0.f, xc3 = 0.f;
  float xn0 = 0.f, xn1 = 0.f, xn2 = 0.f, xn3 = 0.f;
  if (tid < 256) {
    const size_t xb = ((size_t)b0 + brow) * 2048 + j0 + jc;   // t = 0
    xc0 = xg[xb];
    xc1 = xg[xb + 512];
    xc2 = xg[xb + 1024];
    xc3 = xg[xb + 1536];
  }

  for (int t = 0; t < TT; ++t) {
    const int rbuf = t & 1;
    const int wbuf = rbuf ^ 1;

    // issue xg prefetch for t+1 (in flight across poll/MFMA/cell)
    if (tid < 256) {
      const int tn = (t + 1 < TT) ? t + 1 : t;
      const size_t xb = ((size_t)tn * BB + b0 + brow) * 2048 + j0 + jc;
      xn0 = xg[xb];
      xn1 = xg[xb + 512];
      xn2 = xg[xb + 1024];
      xn3 = xg[xb + 1536];
    }

    f32x4 hh = {0.f, 0.f, 0.f, 0.f}, lh = {0.f, 0.f, 0.f, 0.f}, hl = {0.f, 0.f, 0.f, 0.f};

    if (t > 0) {
      // --- poll tagged h_{t-1} (this thread's 16 dwords as 8 u64) ---
      const uint32_t tagp = (((uint32_t)(t - 1)) >> 1) & 3u;
      const uint32_t EXd = ((tagp & 1u) << 14) | ((tagp >> 1) << 30);
      const uint64_t EX2 = ((uint64_t)EXd << 32) | EXd;
      const uint64_t MK2 = 0x4000400040004000ull;
      const unsigned long long* pb =
          (const unsigned long long*)(hbase + (size_t)rbuf * (GR2 * HH)) +
          (size_t)tid * 8;
      uint64_t w[8];
      for (;;) {
#pragma unroll
        for (int q = 0; q < 8; ++q)
          w[q] = __hip_atomic_load(pb + q, __ATOMIC_RELAXED, __HIP_MEMORY_SCOPE_AGENT);
        uint64_t bad = 0;
#pragma unroll
        for (int q = 0; q < 8; ++q) bad |= (w[q] ^ EX2);
        if ((bad & MK2) == 0ull) break;
      }

      // --- clear tags, pack hi/lo, write LDS tile (swizzled) ---
      {
        const uint32_t CM = ~0x40004000u;
        uint32_t d[16];
#pragma unroll
        for (int q = 0; q < 8; ++q) {
          d[2 * q] = (uint32_t)w[q] & CM;
          d[2 * q + 1] = (uint32_t)(w[q] >> 32) & CM;
        }
        uint32_t hw[8], lw[8];
#pragma unroll
        for (int j = 0; j < 8; ++j) {
          hw[j] = (d[2 * j] & 0xFFFFu) | (d[2 * j + 1] << 16);
          lw[j] = (d[2 * j] >> 16) | (d[2 * j + 1] & 0xFFFF0000u);
        }
        const int rrow = tid >> 5;            // 32 threads per 512-dword row
        const int colb = (tid & 31) * 32;     // byte col of first 16B chunk
        const int base = rrow * 1024;
        const int swz = (rrow & 7) << 4;
        *(uint4*)((char*)AH + base + (colb ^ swz)) = make_uint4(hw[0], hw[1], hw[2], hw[3]);
        *(uint4*)((char*)AH + base + ((colb + 16) ^ swz)) = make_uint4(hw[4], hw[5], hw[6], hw[7]);
        *(uint4*)((char*)AL + base + (colb ^ swz)) = make_uint4(lw[0], lw[1], lw[2], lw[3]);
        *(uint4*)((char*)AL + base + ((colb + 16) ^ swz)) = make_uint4(lw[4], lw[5], lw[6], lw[7]);
      }
    }
    __syncthreads();   // B1: A-tile ready (also len_l at t=0)

    if (t > 0) {
#pragma unroll
      for (int ksl = 0; ksl < 8; ++ksl) {
        const int off = ((kh * 8 + ksl) * 64 + achk) ^ axr;
        short8 ah = *(const short8*)(rowH + off);
        short8 al = *(const short8*)(rowL + off);
        hh = __builtin_amdgcn_mfma_f32_16x16x32_bf16(ah, bhh[ksl], hh, 0, 0, 0);
        lh = __builtin_amdgcn_mfma_f32_16x16x32_bf16(al, bhh[ksl], lh, 0, 0, 0);
        hl = __builtin_amdgcn_mfma_f32_16x16x32_bf16(ah, bhl[ksl], hl, 0, 0, 0);
      }
    }

    // --- exchange partial preacts (all 16 C rows real) ---
    {
      const int crow = (lane >> 4) << 2;
      const int ccol = lane & 15;
#pragma unroll
      for (int r = 0; r < 4; ++r) ex[wave][crow + r][ccol] = hh[r] + lh[r] + hl[r];
    }
    __syncthreads();   // B2: ex ready; A-tile reads complete

    // --- cell update (16x16 = 256 threads); tagged h store ---
    if (tid < 256) {
      const float p0 = ex[0][brow][jc] + ex[1][brow][jc] + xc0;
      const float p1 = ex[2][brow][jc] + ex[3][brow][jc] + xc1;
      const float p2 = ex[4][brow][jc] + ex[5][brow][jc] + xc2;
      const float p3 = ex[6][brow][jc] + ex[7][brow][jc] + xc3;
      const float ig = sigf(p0);
      const float fg = sigf(p1);
      const float cc = tanh_(p2);
      const float og = sigf(p3);
      const float co = c_st[brow][jc];
      const float ct = fg * co + ig * cc;
      const float ht = og * tanh_(ct);
      const bool m = (t < len_l[brow]);
      const float cn = m ? ct : co;
      const float hn = m ? ht : h_st[brow][jc];
      c_st[brow][jc] = cn;
      h_st[brow][jc] = hn;
      out[((size_t)t * BB + b0 + brow) * HH + j0 + jc] = m ? ht : 0.0f;
      uint16_t ph, pl;
      split2(hn, ph, pl);   // |hn| <= 1.0 -> bit14 of ph and pl are 0
      const uint32_t tagw = (((uint32_t)t) >> 1) & 3u;
      const uint32_t TB = ((tagw & 1u) << 14) | ((tagw >> 1) << 30);
      __hip_atomic_store(hbase + (size_t)wbuf * (GR2 * HH) + brow * HH + j0 + jc,
                         ((uint32_t)ph | ((uint32_t)pl << 16)) | TB,
                         __ATOMIC_RELAXED, __HIP_MEMORY_SCOPE_AGENT);
      xc0 = xn0;
      xc1 = xn1;
      xc2 = xn2;
      xc3 = xn3;
    }
  }
}

// ------------------------- fallback: verbatim R4 -------------------------
#define LOAD_XP(tt)                                                            \
  _Pragma("unroll") for (int i = 0; i < 2; ++i) {                              \
    const int flat4 = i * 2048 + tid * 4;                                      \
    const int row = flat4 >> 9;                                                \
    const int col = flat4 & 511;                                               \
    xp[i] = *(const float4*)(x + ((size_t)(tt) * BB + b0 + row) * DD + col);   \
  }

#define STAGE_XP()                                                             \
  _Pragma("unroll") for (int i = 0; i < 2; ++i) {                              \
    const int flat4 = i * 2048 + tid * 4;                                      \
    const int row = flat4 >> 9;                                                \
    const int col = flat4 & 511;                                               \
    uint16_t h0, l0, h1, l1, h2, l2, h3, l3;                                   \
    split2(xp[i].x, h0, l0);                                                   \
    split2(xp[i].y, h1, l1);                                                   \
    split2(xp[i].z, h2, l2);                                                   \
    split2(xp[i].w, h3, l3);                                                   \
    const uint32_t hw0 = (uint32_t)h0 | ((uint32_t)h1 << 16);                  \
    const uint32_t hw1 = (uint32_t)h2 | ((uint32_t)h3 << 16);                  \
    const uint32_t lw0 = (uint32_t)l0 | ((uint32_t)l1 << 16);                  \
    const uint32_t lw1 = (uint32_t)l2 | ((uint32_t)l3 << 16);                  \
    const int off = row * 1024 + ((col * 2) ^ (row << 4));                     \
    *(uint2*)((char*)AH + off) = make_uint2(hw0, hw1);                         \
    *(uint2*)((char*)AL + off) = make_uint2(lw0, lw1);                         \
  }

#define X_MFMA()                                                               \
  hh = (f32x4){0.f, 0.f, 0.f, 0.f};                                           \
  lh = (f32x4){0.f, 0.f, 0.f, 0.f};                                           \
  hl = (f32x4){0.f, 0.f, 0.f, 0.f};                                           \
  _Pragma("unroll") for (int ksl = 0; ksl < 8; ++ksl) {                        \
    const int off = ((kh * 8 + ksl) * 64 + achk) ^ axr;                        \
    short8 ah = *(const short8*)(rowH + off);                                  \
    short8 al = *(const short8*)(rowL + off);                                  \
    hh = __builtin_amdgcn_mfma_f32_16x16x32_bf16(ah, bxh[ksl], hh, 0, 0, 0);   \
    lh = __builtin_amdgcn_mfma_f32_16x16x32_bf16(al, bxh[ksl], lh, 0, 0, 0);   \
    hl = __builtin_amdgcn_mfma_f32_16x16x32_bf16(ah, bxl[ksl], hl, 0, 0, 0);   \
  }

__global__ __launch_bounds__(NTHR, 2) void lstm_r4(
    const float* __restrict__ x, const int* __restrict__ len,
    const float* __restrict__ bias, const uint32_t* __restrict__ fragWx,
    const uint32_t* __restrict__ fragWh, uint32_t* __restrict__ h_pair,
    float* __restrict__ out) {
  const int tid = threadIdx.x;
  const int lane = tid & 63;
  const int wave = tid >> 6;
  const int gp = wave >> 1;
  const int kh = wave & 1;
  const int group = blockIdx.x & 7;
  const int jblk = blockIdx.x >> 3;
  const int b0 = group * GR4;
  const int j0 = jblk << 4;
  uint32_t* hbase = h_pair + (size_t)group * 2 * (GR4 * HH);

  __shared__ uint16_t AH[GR4 * 512];
  __shared__ uint16_t AL[GR4 * 512];
  __shared__ float ex[8][GR4][16];
  __shared__ float c_st[GR4][16];
  __shared__ float h_st[GR4][16];
  __shared__ float bias_l[4][16];
  __shared__ int len_l[GR4];

  if (tid < GR4 * 16) {
    c_st[tid >> 4][tid & 15] = 0.0f;
    h_st[tid >> 4][tid & 15] = 0.0f;
  }
  if (tid < 64) bias_l[tid >> 4][tid & 15] = bias[(size_t)(tid >> 4) * HH + j0 + (tid & 15)];
  if (tid < GR4) len_l[tid] = len[b0 + tid];

  short8 bxh[8], bxl[8], bhh[8], bhl[8];
  {
    const int nblk = gp * 32 + jblk;
#pragma unroll
    for (int ksl = 0; ksl < 8; ++ksl) {
      const size_t idx = ((size_t)(nblk * 16 + kh * 8 + ksl) * 64 + lane) * 8;
      bxh[ksl] = __builtin_bit_cast(short8, *(const uint4*)(fragWx + idx));
      bxl[ksl] = __builtin_bit_cast(short8, *(const uint4*)(fragWx + idx + 4));
      bhh[ksl] = __builtin_bit_cast(short8, *(const uint4*)(fragWh + idx));
      bhl[ksl] = __builtin_bit_cast(short8, *(const uint4*)(fragWh + idx + 4));
    }
  }

  const int arow = lane & 7;
  const int achk = (lane >> 4) << 4;
  const int axr = arow << 4;
  const char* rowH = (const char*)AH + arow * 1024;
  const char* rowL = (const char*)AL + arow * 1024;

  f32x4 hh = {0.f, 0.f, 0.f, 0.f}, lh = {0.f, 0.f, 0.f, 0.f}, hl = {0.f, 0.f, 0.f, 0.f};
  float4 xp[2];

  LOAD_XP(0);
  __syncthreads();
  STAGE_XP();
  __syncthreads();
  X_MFMA();
  LOAD_XP(1);

  for (int t = 0; t < TT; ++t) {
    const int rbuf = t & 1;
    const int wbuf = rbuf ^ 1;

    if (t > 0) {
      const uint32_t tagp = (((uint32_t)(t - 1)) >> 1) & 3u;
      const uint32_t EXd = ((tagp & 1u) << 14) | ((tagp >> 1) << 30);
      const uint64_t EX2 = ((uint64_t)EXd << 32) | EXd;
      const uint64_t MK2 = 0x4000400040004000ull;
      const unsigned long long* pb =
          (const unsigned long long*)(hbase + (size_t)rbuf * (GR4 * HH)) +
          (size_t)tid * 4;
      uint64_t w0, w1, w2, w3;
      for (;;) {
        w0 = __hip_atomic_load(pb + 0, __ATOMIC_RELAXED, __HIP_MEMORY_SCOPE_AGENT);
        w1 = __hip_atomic_load(pb + 1, __ATOMIC_RELAXED, __HIP_MEMORY_SCOPE_AGENT);
        w2 = __hip_atomic_load(pb + 2, __ATOMIC_RELAXED, __HIP_MEMORY_SCOPE_AGENT);
        w3 = __hip_atomic_load(pb + 3, __ATOMIC_RELAXED, __HIP_MEMORY_SCOPE_AGENT);
        const uint64_t bad =
            (((w0 ^ EX2) | (w1 ^ EX2) | (w2 ^ EX2) | (w3 ^ EX2)) & MK2);
        if (bad == 0ull) break;
      }
      __syncthreads();

      {
        const uint32_t CM = ~0x40004000u;
        uint32_t d0 = (uint32_t)w0 & CM, d1 = (uint32_t)(w0 >> 32) & CM;
        uint32_t d2 = (uint32_t)w1 & CM, d3 = (uint32_t)(w1 >> 32) & CM;
        uint32_t d4 = (uint32_t)w2 & CM, d5 = (uint32_t)(w2 >> 32) & CM;
        uint32_t d6 = (uint32_t)w3 & CM, d7 = (uint32_t)(w3 >> 32) & CM;
        const uint32_t hi0 = (d0 & 0xFFFFu) | (d1 << 16);
        const uint32_t lo0 = (d0 >> 16) | (d1 & 0xFFFF0000u);
        const uint32_t hi1 = (d2 & 0xFFFFu) | (d3 << 16);
        const uint32_t lo1 = (d2 >> 16) | (d3 & 0xFFFF0000u);
        const uint32_t hi2 = (d4 & 0xFFFFu) | (d5 << 16);
        const uint32_t lo2 = (d4 >> 16) | (d5 & 0xFFFF0000u);
        const uint32_t hi3 = (d6 & 0xFFFFu) | (d7 << 16);
        const uint32_t lo3 = (d6 >> 16) | (d7 & 0xFFFF0000u);
        const int woff = wave * 1024 + ((lane * 16) ^ (wave << 4));
        *(uint4*)((char*)AH + woff) = make_uint4(hi0, hi1, hi2, hi3);
        *(uint4*)((char*)AL + woff) = make_uint4(lo0, lo1, lo2, lo3);
      }
      __syncthreads();

#pragma unroll
      for (int ksl = 0; ksl < 8; ++ksl) {
        const int off = ((kh * 8 + ksl) * 64 + achk) ^ axr;
        short8 ah = *(const short8*)(rowH + off);
        short8 al = *(const short8*)(rowL + off);
        hh = __builtin_amdgcn_mfma_f32_16x16x32_bf16(ah, bhh[ksl], hh, 0, 0, 0);
        lh = __builtin_amdgcn_mfma_f32_16x16x32_bf16(al, bhh[ksl], lh, 0, 0, 0);
        hl = __builtin_amdgcn_mfma_f32_16x16x32_bf16(ah, bhl[ksl], hl, 0, 0, 0);
      }
    }

    {
      const int crow = (lane >> 4) << 2;
      const int ccol = lane & 15;
      if (crow < GR4) {
#pragma unroll
        for (int r = 0; r < 4; ++r) ex[wave][crow + r][ccol] = hh[r] + lh[r] + hl[r];
      }
    }
    __syncthreads();

    if (tid < GR4 * 16) {
      const int brow = tid >> 4;
      const int jc = tid & 15;
      const float p0 = ex[0][brow][jc] + ex[1][brow][jc] + bias_l[0][jc];
      const float p1 = ex[2][brow][jc] + ex[3][brow][jc] + bias_l[1][jc];
      const float p2 = ex[4][brow][jc] + ex[5][brow][jc] + bias_l[2][jc];
      const float p3 = ex[6][brow][jc] + ex[7][brow][jc] + bias_l[3][jc];
      const float ig = sigf(p0);
      const float fg = sigf(p1);
      const float cc = tanh_(p2);
      const float og = sigf(p3);
      const float co = c_st[brow][jc];
      const float ct = fg * co + ig * cc;
      const float ht = og * tanh_(ct);
      const bool m = (t < len_l[brow]);
      const float cn = m ? ct : co;
      const float hn = m ? ht : h_st[brow][jc];
      c_st[brow][jc] = cn;
      h_st[brow][jc] = hn;
      out[((size_t)t * BB + b0 + brow) * HH + j0 + jc] = m ? ht : 0.0f;
      uint16_t ph, pl;
      split2(hn, ph, pl);
      const uint32_t tagw = (((uint32_t)t) >> 1) & 3u;
      const uint32_t TB = ((tagw & 1u) << 14) | ((tagw >> 1) << 30);
      const uint32_t hv = ((uint32_t)ph | ((uint32_t)pl << 16)) | TB;
      __hip_atomic_store(hbase + (size_t)wbuf * (GR4 * HH) + brow * HH + j0 + jc,
                         hv, __ATOMIC_RELAXED, __HIP_MEMORY_SCOPE_AGENT);
    }

    if (t + 1 < TT) {
      STAGE_XP();
      __syncthreads();
      X_MFMA();
      LOAD_XP(min(t + 2, TT - 1));
    }
  }
}
#undef LOAD_XP
#undef STAGE_XP
#undef X_MFMA

extern "C" void kernel_launch(void* const* d_in, const int* in_sizes, int n_in,
                              void* d_out, int out_size, void* d_ws, size_t ws_size,
                              hipStream_t stream) {
  const float* x = (const float*)d_in[0];
  const int* len = (const int*)d_in[1];
  const float* Wx = (const float*)d_in[2];    // [2048][512]
  const float* Wh = (const float*)d_in[3];    // [2048][512]
  const float* bias = (const float*)d_in[4];  // [2048]
  float* out = (float*)d_out;

  const size_t FRAG_DW = (size_t)128 * 16 * 64 * 8;   // 4 MB each
  const size_t HP_DW = 65536;                          // 256 KB (both layouts)
  const size_t XG_DW = (size_t)TT * BB * 2048;         // 256 MB fp32
  uint32_t* fragWx = (uint32_t*)d_ws;
  uint32_t* fragWh = fragWx + FRAG_DW;
  uint32_t* h_pair = fragWh + FRAG_DW;
  float* xg = (float*)(h_pair + HP_DW);
  const size_t need = (2 * FRAG_DW + HP_DW + XG_DW) * 4;

  // 0xFF -> tag bits = 3 in every dword: never matches the first expected
  // tags and is overwritten >=2x before tag 3 recurs.
  hipMemsetAsync(h_pair, 0xFF, HP_DW * 4, stream);

  build_frags<<<dim3(512), dim3(256), 0, stream>>>(Wx, fragWx);
  build_frags<<<dim3(512), dim3(256), 0, stream>>>(Wh, fragWh);

  if (ws_size >= need) {
    xg_gemm<<<dim3(TT), dim3(NTHR), 0, stream>>>(x, bias, fragWx, xg);
    void* args[] = {(void*)&len, (void*)&fragWh, (void*)&xg, (void*)&h_pair,
                    (void*)&out};
    hipLaunchCooperativeKernel((void*)lstm2, dim3(NWG2), dim3(NTHR), args, 0, stream);
  } else {
    void* args[] = {(void*)&x,      (void*)&len,    (void*)&bias, (void*)&fragWx,
                    (void*)&fragWh, (void*)&h_pair, (void*)&out};
    hipLaunchCooperativeKernel((void*)lstm_r4, dim3(NWG4), dim3(NTHR), args, 0, stream);
  }
}